// Round 10
// baseline (539.594 us; speedup 1.0000x reference)
//
#include <hip/hip_runtime.h>
#include <hip/hip_cooperative_groups.h>
#include <hip/hip_bf16.h>

namespace cg = cooperative_groups;

// GraphNet2: N=50000 nodes, E=1.6M edges, F=128.
// R1-R8: LDS-privatized scatter, j-split encode, transposed replica,
//   reg-rich head -> 153.5us across 4 kernels; interior micro-opts stopped
//   paying; ~40us sits in 3 kernel boundaries.
// R9: cooperative mega-kernel REGRESSED to 425us. Counters: VGPR_Count=36
//   -> P1 gemv accumulators spilled to scratch inside the k-loop. Cause:
//   dynamic LDS hides the 1-block/CU constraint, so the compiler allocated
//   registers for 8 waves/EU occupancy.
// R10: same kernel + __launch_bounds__(1024, 4): 4 waves/EU = 1 block/CU
//   (what the 100KB LDS forces anyway) -> VGPR cap ~128, no spill. This is
//   the actual test of the fusion hypothesis.

#define NF 128
#define DENC 32
#define DEMB 12
#define DH 128

#define NSLICE 128       // edge slices (replica rows)
#define NRANGE 2         // node ranges
#define R_SCAT 25024     // LDS table entries (100096 B dynamic), %64==0
#define ROWB (NSLICE*64) // floats per node-chunk in rep2 (8192)
#define GRID_X (NSLICE*NRANGE)  // 256
#define BLK 1024

struct KArgs {
    const float* nodes; const int* senders; const int* recvs;
    const float* W_enc; const float* b_enc;
    const float* W_inf; const float* b_inf;
    const float* W_emb; const float* b_emb;
    const float* W1; const float* b1;
    const float* W2; const float* b2;
    const float* Wy; const float* by;
    const float* Wx; const float* bx;
    float* p; float* inflb; float* embT; float* rep2; float* psum;
    float* out; int n_nodes; int n_edges;
};

// GEMV over one full node row (k=0..127): acc[j] += x[k]*W[k*LDW+jbase+j].
// jbase wave-uniform -> W/bias loads stay scalar. Returns x[127].
template <int NJ, int LDW>
__device__ __forceinline__ void gemv_rows(
    const float4* __restrict__ x4p, const float* __restrict__ W,
    int jbase, const float* __restrict__ bias, float* acc, float& x_last)
{
#pragma unroll
    for (int j = 0; j < NJ; j++) acc[j] = bias[jbase + j];
#pragma unroll 2
    for (int c = 0; c < 8; c++) {
        float4 xa = x4p[4 * c + 0];
        float4 xb = x4p[4 * c + 1];
        float4 xc = x4p[4 * c + 2];
        float4 xd = x4p[4 * c + 3];
        float xs[16] = {xa.x, xa.y, xa.z, xa.w, xb.x, xb.y, xb.z, xb.w,
                        xc.x, xc.y, xc.z, xc.w, xd.x, xd.y, xd.z, xd.w};
#pragma unroll
        for (int u = 0; u < 16; u++) {
            const int k = 16 * c + u;
#pragma unroll
            for (int j = 0; j < NJ; j++)
                acc[j] = fmaf(xs[u], W[k * LDW + jbase + j], acc[j]);
        }
        if (c == 7) x_last = xd.w;
    }
}

__global__ __launch_bounds__(BLK, 4) void fused(KArgs a)
{
    extern __shared__ float smem[];          // R_SCAT floats (100096 B)
    cg::grid_group grid = cg::this_grid();

    const int tid  = threadIdx.x;
    const int q    = tid >> 8;               // sub-block 0..3 (256 thr each)
    const int lane = tid & 63;
    const int wv   = (tid >> 6) & 3;         // wave within sub
    const int nb64 = (a.n_nodes + 63) >> 6;  // 782

    // ================= Phase 1: node encode (j-split) =================
    {
        float* tabp = smem;                  // [4][3][64]
        const int g    = blockIdx.x * 4 + q; // group 0..1023
        const int node = g * 64 + lane;
        const bool son = (g < nb64);
        const bool ok  = son && (node < a.n_nodes);
        float x127 = 0.f;
        if (son) {
            const float4* x4p = ok ? (const float4*)(a.nodes + (size_t)node * NF)
                                   : (const float4*)a.nodes;
            if (wv == 3) {
                float acc[DEMB];
                gemv_rows<DEMB, DEMB>(x4p, a.W_emb, 0, a.b_emb, acc, x127);
                if (ok) {
#pragma unroll
                    for (int j = 0; j < DEMB; j++)
                        a.embT[(size_t)j * a.n_nodes + node] = acc[j];
                }
            } else {
                const int jbase = __builtin_amdgcn_readfirstlane(wv * 11);
                float pp = 0.f;
                if (wv == 2) {
                    float acc[10];
                    gemv_rows<10, DENC>(x4p, a.W_enc, jbase, a.b_enc, acc, x127);
#pragma unroll
                    for (int j = 0; j < 10; j++)
                        pp += fmaxf(acc[j], 0.f) * a.W_inf[jbase + j];
                } else {
                    float acc[11];
                    gemv_rows<11, DENC>(x4p, a.W_enc, jbase, a.b_enc, acc, x127);
#pragma unroll
                    for (int j = 0; j < 11; j++)
                        pp += fmaxf(acc[j], 0.f) * a.W_inf[jbase + j];
                }
                tabp[(q * 3 + wv) * 64 + lane] = pp;
            }
        }
        __syncthreads();
        if (son && wv == 0 && ok) {
            float pn = tabp[(q * 3 + 0) * 64 + lane]
                     + tabp[(q * 3 + 1) * 64 + lane]
                     + tabp[(q * 3 + 2) * 64 + lane];
            a.p[node] = pn;
            a.inflb[node] = pn + x127 * a.W_inf[DENC] + a.b_inf[0];
        }
    }
    __threadfence();
    grid.sync();

    // ================= Phase 2: LDS edge scatter =================
    {
        float* tab = smem;                   // R_SCAT floats
        const int slice = blockIdx.x >> 1;   // 0..127
        const int rng_i = blockIdx.x & 1;    // 0..1
        const int e0 = (int)((long long)a.n_edges * slice / NSLICE);
        const int e1 = (int)((long long)a.n_edges * (slice + 1) / NSLICE);
        const int lo = rng_i * R_SCAT;
        const int rng = min(R_SCAT, a.n_nodes - lo);

        float4* tab4 = (float4*)tab;
        for (int i = tid; i < (rng + 3) / 4; i += BLK)
            tab4[i] = make_float4(0.f, 0.f, 0.f, 0.f);
        __syncthreads();

        const int ae0 = (e0 + 3) & ~3;
        const int ae1 = e1 & ~3;
        for (int e = e0 + tid; e < ae0; e += BLK) {
            unsigned rr = (unsigned)(a.recvs[e] - lo);
            if (rr < (unsigned)rng) atomicAdd(&tab[rr], a.p[a.senders[e]]);
        }
        const int4* r4 = (const int4*)a.recvs;
        const int4* s4 = (const int4*)a.senders;
        for (int i = ae0 / 4 + tid; i < ae1 / 4; i += BLK) {
            int4 r = r4[i];
            int4 s = s4[i];
            unsigned rr;
            rr = (unsigned)(r.x - lo); if (rr < (unsigned)rng) atomicAdd(&tab[rr], a.p[s.x]);
            rr = (unsigned)(r.y - lo); if (rr < (unsigned)rng) atomicAdd(&tab[rr], a.p[s.y]);
            rr = (unsigned)(r.z - lo); if (rr < (unsigned)rng) atomicAdd(&tab[rr], a.p[s.z]);
            rr = (unsigned)(r.w - lo); if (rr < (unsigned)rng) atomicAdd(&tab[rr], a.p[s.w]);
        }
        for (int e = ae1 + tid; e < e1; e += BLK) {
            unsigned rr = (unsigned)(a.recvs[e] - lo);
            if (rr < (unsigned)rng) atomicAdd(&tab[rr], a.p[a.senders[e]]);
        }
        __syncthreads();

        // writeback: rep2[chunk][slice][col]; lo%64==0
        const int g4base = lo >> 2;
        for (int i4 = tid; i4 < rng / 4; i4 += BLK) {
            const int g4    = g4base + i4;
            const int chunk = g4 >> 4;
            const int col4  = g4 & 15;
            ((float4*)a.rep2)[(size_t)chunk * (ROWB / 4) + slice * 16 + col4] = tab4[i4];
        }
        for (int i = (rng & ~3) + tid; i < rng; i += BLK) {
            const int g = lo + i;
            a.rep2[(size_t)(g >> 6) * ROWB + slice * 64 + (g & 63)] = tab[i];
        }
    }
    __threadfence();
    grid.sync();

    // ======= Phase 3: replica reduce + block softmax partials =======
    {
        float* t3 = smem + q * 256;          // per-sub [4][64]
        const int chunk = blockIdx.x * 4 + q;
        const bool son  = (chunk < nb64);
        const int node  = chunk * 64 + lane;
        const bool ok   = son && (node < a.n_nodes);

        if (son) {
            const float* cb = a.rep2 + (size_t)chunk * ROWB;
            const int s0 = lane >> 4;        // 0..3
            const int c4 = lane & 15;        // 0..15
            float4 ac = make_float4(0.f, 0.f, 0.f, 0.f);
#pragma unroll
            for (int i = 0; i < 8; i++) {
                const int slice = 32 * wv + s0 + 4 * i;
                float4 v = ((const float4*)(cb + slice * 64))[c4];
                ac.x += v.x; ac.y += v.y; ac.z += v.z; ac.w += v.w;
            }
#pragma unroll
            for (int off = 16; off <= 32; off <<= 1) {
                ac.x += __shfl_xor(ac.x, off, 64);
                ac.y += __shfl_xor(ac.y, off, 64);
                ac.z += __shfl_xor(ac.z, off, 64);
                ac.w += __shfl_xor(ac.w, off, 64);
            }
            if (s0 == 0) {
                t3[wv * 64 + 4 * c4 + 0] = ac.x;
                t3[wv * 64 + 4 * c4 + 1] = ac.y;
                t3[wv * 64 + 4 * c4 + 2] = ac.z;
                t3[wv * 64 + 4 * c4 + 3] = ac.w;
            }
        }
        __syncthreads();
        if (son && wv == 0) {
            float infl = ok ? a.inflb[node] + t3[lane] + t3[64 + lane]
                              + t3[128 + lane] + t3[192 + lane]
                            : -1e30f;
            float m = infl;
#pragma unroll
            for (int off = 32; off; off >>= 1)
                m = fmaxf(m, __shfl_down(m, off, 64));
            m = __shfl(m, 0, 64);

            const float w = ok ? expf(infl - m) : 0.f;
            float v13[13];
            v13[0] = w;
#pragma unroll
            for (int j = 0; j < DEMB; j++)
                v13[1 + j] = ok ? w * a.embT[(size_t)j * a.n_nodes + node] : 0.f;
#pragma unroll
            for (int v = 0; v < 13; v++) {
                float x = v13[v];
#pragma unroll
                for (int off = 32; off; off >>= 1)
                    x += __shfl_down(x, off, 64);
                v13[v] = x;
            }
            if (lane == 0) {
                a.psum[chunk * 14] = m;
#pragma unroll
                for (int v = 0; v < 13; v++)
                    a.psum[chunk * 14 + 1 + v] = v13[v];
            }
        }
    }
    __threadfence();
    grid.sync();

    // ============ Phase 4: merge partials + MLP head (block 0) ============
    if (blockIdx.x == 0) {
        float* sred = smem;                  // [16*13]
        float* tot  = sred + 16 * 13;        // [13]
        float* gv   = tot + 13;              // [12]
        float* h1   = gv + 12;               // [128]
        float* part = h1 + 128;              // [8*128]
        float* h2   = part + 8 * 128;        // [128]
        float* wred = h2 + 128;              // [2*5]
        const int wvid = tid >> 6;           // 0..15

        float m = (tid < nb64) ? a.psum[tid * 14] : -1e30f;
#pragma unroll
        for (int off = 32; off; off >>= 1)
            m = fmaxf(m, __shfl_down(m, off, 64));
        if (lane == 0) sred[wvid] = m;
        __syncthreads();
        float M = sred[0];
#pragma unroll
        for (int i = 1; i < 16; i++) M = fmaxf(M, sred[i]);
        __syncthreads();

        float acc[13];
#pragma unroll
        for (int v = 0; v < 13; v++) acc[v] = 0.f;
        if (tid < nb64) {
            float sc = expf(a.psum[tid * 14] - M);
#pragma unroll
            for (int v = 0; v < 13; v++)
                acc[v] = sc * a.psum[tid * 14 + 1 + v];
        }
#pragma unroll
        for (int v = 0; v < 13; v++) {
            float x = acc[v];
#pragma unroll
            for (int off = 32; off; off >>= 1)
                x += __shfl_down(x, off, 64);
            if (lane == 0) sred[wvid * 13 + v] = x;
        }
        __syncthreads();
        if (tid < 13) {
            float s = 0.f;
#pragma unroll
            for (int i = 0; i < 16; i++) s += sred[i * 13 + tid];
            tot[tid] = s;
        }
        __syncthreads();
        if (tid < DEMB) gv[tid] = tot[1 + tid] / tot[0];
        __syncthreads();

        if (tid < DH) {
            float s1 = a.b1[tid];
#pragma unroll
            for (int i = 0; i < DEMB; i++)
                s1 = fmaf(gv[i], a.W1[i * DH + tid], s1);
            h1[tid] = fmaxf(s1, 0.f);
        }
        __syncthreads();

        {
            const int ks = tid >> 7;         // 0..7
            const int o  = tid & 127;
            float s = 0.f;
            const float* w2 = a.W2 + (size_t)(16 * ks) * DH + o;
#pragma unroll 8
            for (int i = 0; i < 16; i++)
                s = fmaf(h1[16 * ks + i], w2[i * DH], s);
            part[ks * 128 + o] = s;
        }
        __syncthreads();
        if (tid < DH) {
            float s = a.b2[tid];
#pragma unroll
            for (int k = 0; k < 8; k++) s += part[k * 128 + tid];
            h2[tid] = fmaxf(s, 0.f);
        }
        __syncthreads();

        if (tid < DH) {
            const float v = h2[tid];
            float pr[5];
#pragma unroll
            for (int j = 0; j < 4; j++) pr[j] = v * a.Wx[tid * 4 + j];
            pr[4] = v * a.Wy[tid];
#pragma unroll
            for (int j = 0; j < 5; j++) {
                float x = pr[j];
#pragma unroll
                for (int off = 32; off; off >>= 1)
                    x += __shfl_down(x, off, 64);
                if (lane == 0) wred[wvid * 5 + j] = x;
            }
        }
        __syncthreads();
        if (tid < 4)
            a.out[tid] = (wred[tid] + wred[5 + tid] + a.bx[tid]) / 10.0f;
        else if (tid == 4)
            a.out[4] = wred[4] + wred[9] + a.by[0];
    }
}

extern "C" void kernel_launch(void* const* d_in, const int* in_sizes, int n_in,
                              void* d_out, int out_size, void* d_ws, size_t ws_size,
                              hipStream_t stream) {
    const int n_nodes = in_sizes[0] / NF;   // 50000
    const int n_edges = in_sizes[1];        // 1600000
    const int nb64 = (n_nodes + 63) / 64;   // 782

    float* ws = (float*)d_ws;
    KArgs a;
    a.nodes   = (const float*)d_in[0];
    a.senders = (const int*)d_in[1];
    a.recvs   = (const int*)d_in[2];
    a.W_enc = (const float*)d_in[3];  a.b_enc = (const float*)d_in[4];
    a.W_inf = (const float*)d_in[5];  a.b_inf = (const float*)d_in[6];
    a.W_emb = (const float*)d_in[7];  a.b_emb = (const float*)d_in[8];
    a.W1 = (const float*)d_in[9];     a.b1 = (const float*)d_in[10];
    a.W2 = (const float*)d_in[11];    a.b2 = (const float*)d_in[12];
    a.Wy = (const float*)d_in[13];    a.by = (const float*)d_in[14];
    a.Wx = (const float*)d_in[15];    a.bx = (const float*)d_in[16];
    a.p     = ws;                                 // [N]
    a.inflb = ws + n_nodes;                       // [N]
    a.embT  = ws + 2 * (size_t)n_nodes;           // [12][N]
    a.rep2  = ws + 14 * (size_t)n_nodes;          // [nb64][128][64]
    a.psum  = a.rep2 + (size_t)nb64 * ROWB;       // [nb64*14]
    a.out   = (float*)d_out;
    a.n_nodes = n_nodes;
    a.n_edges = n_edges;

    (void)hipFuncSetAttribute((const void*)fused,
                              hipFuncAttributeMaxDynamicSharedMemorySize,
                              R_SCAT * (int)sizeof(float));

    void* kp[] = { (void*)&a };
    (void)hipLaunchCooperativeKernel((void*)fused, dim3(GRID_X), dim3(BLK),
                                     kp, R_SCAT * sizeof(float), stream);
}

// Round 11
// 150.994 us; speedup vs baseline: 3.5736x; 3.5736x over previous
//
#include <hip/hip_runtime.h>
#include <hip/hip_bf16.h>

// GraphNet2: N=50000 nodes, E=1.6M edges, F=128.
// R1: global atomic scatter 91us (32B/op write-through) -> LDS privatization.
// R2: 128-block scatter, occupancy 9% -> split ranges across blocks.
// R3: k1 k-split spilled (VGPR=32, scratch round-trips) -> 79us.
// R4: k1 j-split (no spill) -> 160us; top-5 = harness 256MiB poison fills.
// R5/R6: k3+k4 fusion regressed +19us; rep2 transpose neutral.
// R7: un-fused, reg-rich k4 -> 156us.
// R8: 1024thr/100KB k2 + float4 k3 -> 153.5us. BEST. All compute kernels
//     below the 43us harness-fill line; top-5 = 100% harness machinery.
// R9/R10: cooperative mega-kernel (256 blk x 1024 thr, grid.sync between
//     phases) catastrophically regressed: 415us interior (VALUBusy 2%,
//     98% stalled, VGPR=36 regardless of launch_bounds) plus a 31ms
//     replay outlier (grid.sync spin fragility under graph replay).
//     Fusion direction abandoned on evidence.
// R11: revert to R8 verbatim. Controllable floor: ~40-50us kernel interiors
//     + ~15-20us launch boundaries vs ~55-60us fixed harness overhead.

#define NF 128
#define DENC 32
#define DEMB 12
#define DH 128

#define NSLICE 128       // replica rows (edge slices)
#define NRANGE 2         // node ranges
#define R_SCAT 25024     // LDS table entries (100096 B dynamic), %64==0
#define ROWB (NSLICE*64) // floats per node-chunk in rep2 (8192)

// GEMV over one node row: acc[j] += x[k] * W[k*LDW + jbase + j], k=0..127.
// jbase is wave-uniform -> W/bias loads are s_loads. Also returns x[127].
template <int NJ, int LDW>
__device__ __forceinline__ void gemv_rows(
    const float4* __restrict__ x4p, const float* __restrict__ W,
    int jbase, const float* __restrict__ bias, float* acc, float& x_last)
{
#pragma unroll
    for (int j = 0; j < NJ; j++) acc[j] = bias[jbase + j];
#pragma unroll 2
    for (int c = 0; c < 8; c++) {
        float4 xa = x4p[4 * c + 0];
        float4 xb = x4p[4 * c + 1];
        float4 xc = x4p[4 * c + 2];
        float4 xd = x4p[4 * c + 3];
        float xs[16] = {xa.x, xa.y, xa.z, xa.w, xb.x, xb.y, xb.z, xb.w,
                        xc.x, xc.y, xc.z, xc.w, xd.x, xd.y, xd.z, xd.w};
#pragma unroll
        for (int u = 0; u < 16; u++) {
            const int k = 16 * c + u;
#pragma unroll
            for (int j = 0; j < NJ; j++)
                acc[j] = fmaf(xs[u], W[k * LDW + jbase + j], acc[j]);
        }
        if (c == 7) x_last = xd.w;
    }
}

// ---------------- K1: per-node encode, 4-way j-split ----------------------
__global__ __launch_bounds__(256) void k1_node(
    const float* __restrict__ nodes,
    const float* __restrict__ W_enc, const float* __restrict__ b_enc,
    const float* __restrict__ W_inf, const float* __restrict__ b_inf,
    const float* __restrict__ W_emb, const float* __restrict__ b_emb,
    float* __restrict__ p, float* __restrict__ inflb, float* __restrict__ embT,
    int n_nodes)
{
    __shared__ float tabp[3][64];
    const int tid  = threadIdx.x;
    const int lane = tid & 63;
    const int wv   = __builtin_amdgcn_readfirstlane(tid >> 6);  // 0..3
    const int node = blockIdx.x * 64 + lane;
    const bool ok  = (node < n_nodes);

    const float4* x4p = ok ? (const float4*)(nodes + (size_t)node * NF)
                           : (const float4*)nodes;

    float x127 = 0.f;
    if (wv == 3) {
        float acc[DEMB];
        gemv_rows<DEMB, DEMB>(x4p, W_emb, 0, b_emb, acc, x127);
        if (ok) {
#pragma unroll
            for (int j = 0; j < DEMB; j++)
                embT[(size_t)j * n_nodes + node] = acc[j];
        }
    } else {
        const int jbase = __builtin_amdgcn_readfirstlane(wv * 11);
        float pp = 0.f;
        if (wv == 2) {
            float acc[10];
            gemv_rows<10, DENC>(x4p, W_enc, jbase, b_enc, acc, x127);
#pragma unroll
            for (int j = 0; j < 10; j++)
                pp += fmaxf(acc[j], 0.f) * W_inf[jbase + j];
        } else {
            float acc[11];
            gemv_rows<11, DENC>(x4p, W_enc, jbase, b_enc, acc, x127);
#pragma unroll
            for (int j = 0; j < 11; j++)
                pp += fmaxf(acc[j], 0.f) * W_inf[jbase + j];
        }
        tabp[wv][lane] = pp;
    }
    __syncthreads();

    if (wv == 0 && ok) {
        float pn = tabp[0][lane] + tabp[1][lane] + tabp[2][lane];
        p[node] = pn;
        inflb[node] = pn + x127 * W_inf[DENC] + b_inf[0];
    }
}

// ---------------- K2: LDS scatter -> transposed replica -------------------
// 256 blocks = 128 edge-slices x 2 range-owners; 1024 thr; 100KB dynamic LDS.
__global__ __launch_bounds__(1024) void k2_scatter(
    const int* __restrict__ senders, const int* __restrict__ recvs,
    const float* __restrict__ p, float* __restrict__ rep2,
    int n_nodes, int n_edges)
{
    extern __shared__ float tab[];           // R_SCAT floats
    const int slice = blockIdx.x >> 1;       // edge slice (0..127)
    const int rng_i = blockIdx.x & 1;        // node range (0..1)
    const int e0 = (int)((long long)n_edges * slice / NSLICE);
    const int e1 = (int)((long long)n_edges * (slice + 1) / NSLICE);
    const int lo = rng_i * R_SCAT;
    const int rng = min(R_SCAT, n_nodes - lo);

    float4* tab4 = (float4*)tab;
    for (int i = threadIdx.x; i < (rng + 3) / 4; i += 1024)
        tab4[i] = make_float4(0.f, 0.f, 0.f, 0.f);
    __syncthreads();

    // aligned int4 main loop + scalar tails (E/NSLICE=12500 %4==0 -> empty)
    const int ae0 = (e0 + 3) & ~3;
    const int ae1 = e1 & ~3;
    for (int e = e0 + (int)threadIdx.x; e < ae0; e += 1024) {
        unsigned rr = (unsigned)(recvs[e] - lo);
        if (rr < (unsigned)rng) atomicAdd(&tab[rr], p[senders[e]]);
    }
    const int4* r4 = (const int4*)recvs;
    const int4* s4 = (const int4*)senders;
    for (int i = ae0 / 4 + (int)threadIdx.x; i < ae1 / 4; i += 1024) {
        int4 r = r4[i];
        int4 s = s4[i];
        unsigned rr;
        rr = (unsigned)(r.x - lo); if (rr < (unsigned)rng) atomicAdd(&tab[rr], p[s.x]);
        rr = (unsigned)(r.y - lo); if (rr < (unsigned)rng) atomicAdd(&tab[rr], p[s.y]);
        rr = (unsigned)(r.z - lo); if (rr < (unsigned)rng) atomicAdd(&tab[rr], p[s.z]);
        rr = (unsigned)(r.w - lo); if (rr < (unsigned)rng) atomicAdd(&tab[rr], p[s.w]);
    }
    for (int e = ae1 + (int)threadIdx.x; e < e1; e += 1024) {
        unsigned rr = (unsigned)(recvs[e] - lo);
        if (rr < (unsigned)rng) atomicAdd(&tab[rr], p[senders[e]]);
    }
    __syncthreads();

    // float4 writeback into rep2[chunk][slice][col]; lo%64==0, rng%4==0
    const int g4base = lo >> 2;
    for (int i4 = threadIdx.x; i4 < rng / 4; i4 += 1024) {
        const int g4    = g4base + i4;
        const int chunk = g4 >> 4;
        const int col4  = g4 & 15;
        ((float4*)rep2)[(size_t)chunk * (ROWB / 4) + slice * 16 + col4] = tab4[i4];
    }
    for (int i = (rng & ~3) + threadIdx.x; i < rng; i += 1024) {
        const int g = lo + i;
        rep2[(size_t)(g >> 6) * ROWB + slice * 64 + (g & 63)] = tab[i];
    }
}

// ---------------- K3: float4 replica reduce + softmax partials ------------
__global__ __launch_bounds__(256) void k3_soft(
    const float* __restrict__ inflb, const float* __restrict__ rep2,
    const float* __restrict__ embT, float* __restrict__ psum, int n_nodes)
{
    __shared__ float tab[4][64];
    const int tid  = threadIdx.x;
    const int lane = tid & 63;
    const int wv   = __builtin_amdgcn_readfirstlane(tid >> 6);
    const int node = blockIdx.x * 64 + lane;
    const bool ok  = (node < n_nodes);

    // phase A: reduce 128 slices of this chunk; wave wv owns 32 slices.
    // lane = s0(2b) x col4(4b): float4 per lane, 8 slice-steps.
    {
        const float* chunk = rep2 + (size_t)blockIdx.x * ROWB;
        const int s0 = lane >> 4;        // 0..3
        const int c4 = lane & 15;        // 0..15
        float4 a = make_float4(0.f, 0.f, 0.f, 0.f);
#pragma unroll
        for (int i = 0; i < 8; i++) {
            const int slice = 32 * wv + s0 + 4 * i;
            float4 v = ((const float4*)(chunk + slice * 64))[c4];
            a.x += v.x; a.y += v.y; a.z += v.z; a.w += v.w;
        }
        // reduce over s0 (lane bits 4-5) via xor butterfly
#pragma unroll
        for (int off = 16; off <= 32; off <<= 1) {
            a.x += __shfl_xor(a.x, off, 64);
            a.y += __shfl_xor(a.y, off, 64);
            a.z += __shfl_xor(a.z, off, 64);
            a.w += __shfl_xor(a.w, off, 64);
        }
        if (s0 == 0) {
            tab[wv][4 * c4 + 0] = a.x;
            tab[wv][4 * c4 + 1] = a.y;
            tab[wv][4 * c4 + 2] = a.z;
            tab[wv][4 * c4 + 3] = a.w;
        }
    }
    __syncthreads();

    // phase B: block softmax partial (wave 0)
    if (wv == 0) {
        float infl = ok ? inflb[node] + tab[0][lane] + tab[1][lane]
                          + tab[2][lane] + tab[3][lane]
                        : -1e30f;
        float m = infl;
#pragma unroll
        for (int off = 32; off; off >>= 1)
            m = fmaxf(m, __shfl_down(m, off, 64));
        m = __shfl(m, 0, 64);

        const float w = ok ? expf(infl - m) : 0.f;
        float v13[13];
        v13[0] = w;
#pragma unroll
        for (int j = 0; j < DEMB; j++)
            v13[1 + j] = ok ? w * embT[(size_t)j * n_nodes + node] : 0.f;

#pragma unroll
        for (int v = 0; v < 13; v++) {
            float x = v13[v];
#pragma unroll
            for (int off = 32; off; off >>= 1)
                x += __shfl_down(x, off, 64);
            v13[v] = x;
        }
        if (lane == 0) {
            psum[blockIdx.x * 14] = m;
#pragma unroll
            for (int v = 0; v < 13; v++)
                psum[blockIdx.x * 14 + 1 + v] = v13[v];
        }
    }
}

// ---------------- K4: merge partials + MLP head (512 thr, reg-rich) -------
__global__ __launch_bounds__(512, 1) void k4_head(
    const float* __restrict__ psum,
    const float* __restrict__ W1, const float* __restrict__ b1,
    const float* __restrict__ W2, const float* __restrict__ b2,
    const float* __restrict__ Wy, const float* __restrict__ by,
    const float* __restrict__ Wx, const float* __restrict__ bx,
    float* __restrict__ out, int nblk)
{
    const int t  = threadIdx.x;
    const int wv = t >> 6;      // 0..7
    const int ln = t & 63;

    __shared__ float sred[8][14];
    __shared__ float tot[14];
    __shared__ float g[DEMB];
    __shared__ float h1[DH];
    __shared__ float part[4][DH];
    __shared__ float h2[DH];
    __shared__ float wred[8][5];

    float m = -1e30f;
    for (int b = t; b < nblk; b += 512) m = fmaxf(m, psum[b * 14]);
#pragma unroll
    for (int off = 32; off; off >>= 1)
        m = fmaxf(m, __shfl_down(m, off, 64));
    if (ln == 0) sred[wv][0] = m;
    __syncthreads();
    float M = sred[0][0];
#pragma unroll
    for (int i = 1; i < 8; i++) M = fmaxf(M, sred[i][0]);
    __syncthreads();

    float acc[13];
#pragma unroll
    for (int v = 0; v < 13; v++) acc[v] = 0.f;
    for (int b = t; b < nblk; b += 512) {
        float sc = expf(psum[b * 14] - M);
#pragma unroll
        for (int v = 0; v < 13; v++)
            acc[v] = fmaf(sc, psum[b * 14 + 1 + v], acc[v]);
    }
#pragma unroll
    for (int v = 0; v < 13; v++) {
        float x = acc[v];
#pragma unroll
        for (int off = 32; off; off >>= 1)
            x += __shfl_down(x, off, 64);
        if (ln == 0) sred[wv][v] = x;
    }
    __syncthreads();
    if (t < 13) {
        float s = 0.f;
#pragma unroll
        for (int i = 0; i < 8; i++) s += sred[i][t];
        tot[t] = s;
    }
    __syncthreads();
    if (t < DEMB) g[t] = tot[1 + t] / tot[0];
    __syncthreads();

    if (t < DH) {
        float s1 = b1[t];
#pragma unroll
        for (int i = 0; i < DEMB; i++) s1 = fmaf(g[i], W1[i * DH + t], s1);
        h1[t] = fmaxf(s1, 0.f);
    }
    __syncthreads();

    {
        const int o  = t & 127;
        const int ks = t >> 7;           // 0..3
        float s = 0.f;
        const float* w2 = W2 + (size_t)(32 * ks) * DH + o;
#pragma unroll 8
        for (int i = 0; i < 32; i++)
            s = fmaf(h1[32 * ks + i], w2[i * DH], s);
        part[ks][o] = s;
    }
    __syncthreads();
    if (t < DH)
        h2[t] = fmaxf(b2[t] + part[0][t] + part[1][t] + part[2][t] + part[3][t], 0.f);
    __syncthreads();

    if (t < DH) {
        const float v = h2[t];
        float pr[5];
#pragma unroll
        for (int j = 0; j < 4; j++) pr[j] = v * Wx[t * 4 + j];
        pr[4] = v * Wy[t];
#pragma unroll
        for (int j = 0; j < 5; j++) {
            float x = pr[j];
#pragma unroll
            for (int off = 32; off; off >>= 1)
                x += __shfl_down(x, off, 64);
            if (ln == 0) wred[wv][j] = x;
        }
    }
    __syncthreads();
    if (t < 4)
        out[t] = (wred[0][t] + wred[1][t] + bx[t]) / 10.0f;
    else if (t == 4)
        out[4] = wred[0][4] + wred[1][4] + by[0];
}

extern "C" void kernel_launch(void* const* d_in, const int* in_sizes, int n_in,
                              void* d_out, int out_size, void* d_ws, size_t ws_size,
                              hipStream_t stream) {
    const float* nodes   = (const float*)d_in[0];
    const int*   senders = (const int*)d_in[1];
    const int*   recvs   = (const int*)d_in[2];
    const float* W_enc   = (const float*)d_in[3];
    const float* b_enc   = (const float*)d_in[4];
    const float* W_inf   = (const float*)d_in[5];
    const float* b_inf   = (const float*)d_in[6];
    const float* W_emb   = (const float*)d_in[7];
    const float* b_emb   = (const float*)d_in[8];
    const float* W1      = (const float*)d_in[9];
    const float* b1      = (const float*)d_in[10];
    const float* W2      = (const float*)d_in[11];
    const float* b2      = (const float*)d_in[12];
    const float* Wy      = (const float*)d_in[13];
    const float* by      = (const float*)d_in[14];
    const float* Wx      = (const float*)d_in[15];
    const float* bx      = (const float*)d_in[16];
    float* out = (float*)d_out;

    const int n_nodes = in_sizes[0] / NF;   // 50000
    const int n_edges = in_sizes[1];        // 1600000
    const int nb64 = (n_nodes + 63) / 64;   // 782

    // workspace layout (floats):
    float* ws    = (float*)d_ws;
    float* p     = ws;                                    // [N]
    float* inflb = ws + n_nodes;                          // [N]
    float* embT  = ws + 2 * (size_t)n_nodes;              // [12][N]
    float* rep2  = ws + 14 * (size_t)n_nodes;             // [nb64][128][64]
    float* psum  = rep2 + (size_t)nb64 * ROWB;            // [nb64*14]

    // allow 100 KB dynamic LDS for k2 (default cap is 64 KB)
    (void)hipFuncSetAttribute((const void*)k2_scatter,
                              hipFuncAttributeMaxDynamicSharedMemorySize,
                              R_SCAT * (int)sizeof(float));

    hipLaunchKernelGGL(k1_node, dim3(nb64), dim3(256), 0, stream,
                       nodes, W_enc, b_enc, W_inf, b_inf, W_emb, b_emb,
                       p, inflb, embT, n_nodes);
    hipLaunchKernelGGL(k2_scatter, dim3(NSLICE * NRANGE), dim3(1024),
                       R_SCAT * sizeof(float), stream,
                       senders, recvs, p, rep2, n_nodes, n_edges);
    hipLaunchKernelGGL(k3_soft, dim3(nb64), dim3(256), 0, stream,
                       inflb, rep2, embT, psum, n_nodes);
    hipLaunchKernelGGL(k4_head, dim3(1), dim3(512), 0, stream,
                       psum, W1, b1, W2, b2, Wy, by, Wx, bx, out, nb64);
}